// Round 1
// baseline (2190.308 us; speedup 1.0000x reference)
//
#include <hip/hip_runtime.h>
#include <hip/hip_fp16.h>

typedef _Float16 f16;
typedef __attribute__((ext_vector_type(8))) _Float16 f16x8;
typedef __attribute__((ext_vector_type(4))) float f32x4;

#define TSTEPS 784
#define BATCH 1024
#define HDIM 512
#define COUT 10
#define ROWS 16
#define LROW 1040           // bytes per LDS h row (512*2 + 16B pad -> bank spread)
#define LBUF (ROWS * LROW)  // 16640 bytes per buffer

// Persistent-T RNN kernel: one WG owns 16 batch rows for all 784 steps.
// h kept in LDS as fp16 (double-buffered). W_rec streamed from L2 as fp16.
// MFMA 16x16x32 f16: C[b, i] += sum_j h[b,j] * W_rec[i,j]
//   A (16xK=32): lane l holds row=l&15, k=(l>>4)*8 + 0..7   (8 f16)
//   B (K=32x16): lane l holds col=l&15, k=(l>>4)*8 + 0..7   (8 f16)
//   C: lane l, reg r -> row=(l>>4)*4+r, col=l&15            (4 f32)
__global__ __launch_bounds__(512, 2)
void rnn_main(const float* __restrict__ x,      // (B, T)
              const float* __restrict__ W_in,   // (H, 1)
              const f16*   __restrict__ Wh,     // (H, H) fp16, row-major W_rec
              const float* __restrict__ W_out,  // (C, H)
              const float* __restrict__ b_out,  // (C)
              const int*   __restrict__ perm,   // (T)
              float* __restrict__ out)          // (B, C)
{
    __shared__ __align__(16) unsigned char hbuf[2 * LBUF];

    const int tid  = threadIdx.x;
    const int wave = tid >> 6;
    const int lane = tid & 63;
    const int l15  = lane & 15;
    const int lhi  = lane >> 4;          // 0..3
    const int b0   = blockIdx.x * ROWS;  // batch row base for this WG
    const int wcol = wave * 64;          // this wave's first output column
    const int rrow = lhi * 4;            // first C-row (batch row) for this lane

    // zero the initial h buffer (h0 = 0)
    for (int i = tid; i < LBUF / 4; i += 512)
        ((unsigned int*)hbuf)[i] = 0u;
    __syncthreads();

    // preload per-lane w_in values for the 4 col-tiles this wave owns
    float win[4];
#pragma unroll
    for (int n = 0; n < 4; ++n)
        win[n] = W_in[wcol + n * 16 + l15];

    // per-n-tile W base pointers (lane-specific, 16B-aligned)
    const f16* wp[4];
#pragma unroll
    for (int n = 0; n < 4; ++n)
        wp[n] = Wh + (size_t)(wcol + n * 16 + l15) * HDIM + lhi * 8;

    unsigned char* cur = hbuf;
    unsigned char* nxt = hbuf + LBUF;

#pragma unroll 1
    for (int t = 0; t < TSTEPS; ++t) {
        const int pt = perm[t];

        // x_t for this lane's 4 batch rows
        float xv[4];
#pragma unroll
        for (int r = 0; r < 4; ++r)
            xv[r] = x[(b0 + rrow + r) * TSTEPS + pt];

        // A fragments: full h rows (shared across all 4 n-tiles)
        f16x8 a[16];
#pragma unroll
        for (int kk = 0; kk < 16; ++kk)
            a[kk] = *(const f16x8*)(cur + l15 * LROW + kk * 64 + lhi * 16);

        f32x4 acc[4];
#pragma unroll
        for (int n = 0; n < 4; ++n) acc[n] = (f32x4){0.f, 0.f, 0.f, 0.f};

#pragma unroll
        for (int n = 0; n < 4; ++n) {
            f16x8 b[16];
#pragma unroll
            for (int kk = 0; kk < 16; ++kk)
                b[kk] = *(const f16x8*)(wp[n] + kk * 32);
#pragma unroll
            for (int kk = 0; kk < 16; ++kk)
                acc[n] = __builtin_amdgcn_mfma_f32_16x16x32_f16(a[kk], b[kk], acc[n], 0, 0, 0);
        }

        // epilogue: injection + relu, store fp16 h_new into next buffer
#pragma unroll
        for (int n = 0; n < 4; ++n) {
#pragma unroll
            for (int r = 0; r < 4; ++r) {
                float v = acc[n][r] + xv[r] * win[n];
                v = fmaxf(v, 0.f);
                *(f16*)(nxt + (rrow + r) * LROW + (wcol + n * 16 + l15) * 2) = (f16)v;
            }
        }
        __syncthreads();
        unsigned char* tswap = cur; cur = nxt; nxt = tswap;
    }

    // final projection: out[b, c] = h_last[b, :] . W_out[c, :] + b_out[c]
    if (tid < ROWS * COUT) {
        const int r = tid / COUT, c = tid % COUT;
        float s = b_out[c];
#pragma unroll 1
        for (int j0 = 0; j0 < HDIM; j0 += 8) {
            f16x8 hv = *(const f16x8*)(cur + r * LROW + j0 * 2);
            const float* wo = W_out + c * HDIM + j0;
#pragma unroll
            for (int jj = 0; jj < 8; ++jj)
                s += (float)hv[jj] * wo[jj];
        }
        out[(b0 + r) * COUT + c] = s;
    }
}

// One-time prep: W_rec fp32 -> fp16 (same row-major layout)
__global__ void cvt_w(const float* __restrict__ W, f16* __restrict__ Wh) {
    const int i = blockIdx.x * 256 + threadIdx.x;
    Wh[i] = (f16)W[i];
}

extern "C" void kernel_launch(void* const* d_in, const int* in_sizes, int n_in,
                              void* d_out, int out_size, void* d_ws, size_t ws_size,
                              hipStream_t stream)
{
    (void)in_sizes; (void)n_in; (void)out_size; (void)ws_size;
    const float* x     = (const float*)d_in[0];
    const float* W_in  = (const float*)d_in[1];
    const float* W_rec = (const float*)d_in[2];
    const float* W_out = (const float*)d_in[3];
    const float* b_out = (const float*)d_in[4];
    const int*   perm  = (const int*)d_in[5];
    float* out = (float*)d_out;
    f16* Wh = (f16*)d_ws;  // 512*512*2 = 512 KB scratch

    cvt_w<<<dim3((HDIM * HDIM) / 256), dim3(256), 0, stream>>>(W_rec, Wh);
    rnn_main<<<dim3(BATCH / ROWS), dim3(512), 0, stream>>>(x, W_in, Wh, W_out, b_out, perm, out);
}